// Round 3
// baseline (149.801 us; speedup 1.0000x reference)
//
#include <hip/hip_runtime.h>
#include <hip/hip_bf16.h>
#include <math.h>

// Problem constants (B,C,H,W) = (2,64,128,128), R=2 -> K=24 neighbors.
#define NNODES 16384            // H*W
#define GNODES 32768            // B*H*W
#define KE 24

// ---------------------------------------------------------------------------
// aux: zpos[k][h] table + W2T [64][32] + wt[mat][c][h] transposed weights
// (contiguous in h so precompute's wave-uniform reads batch as s_load_dwordx16)
// ---------------------------------------------------------------------------
__global__ void aux_k(const float* __restrict__ W1, const float* __restrict__ W2,
                      const float* __restrict__ Wm,
                      float* __restrict__ zpos, float* __restrict__ w2t,
                      float* __restrict__ wt)
{
    int t = threadIdx.x;
    for (int idx = t; idx < KE * 64; idx += 256) {
        int k = idx >> 6, h = idx & 63;
        int kk = k + (k >= 12 ? 1 : 0);       // skip center of 5x5
        int q5 = (kk * 52) >> 8;              // kk/5 for kk<25
        int dy = q5 - 2;
        int dx = kk - 5 * q5 - 2;
        zpos[idx] = W1[h * 130 + 128] * (dx * 0.5f)
                  + W1[h * 130 + 129] * (dy * 0.5f);
    }
    for (int idx = t; idx < 64 * 32; idx += 256) {
        int i = idx >> 5, j = idx & 31;       // w2t[i][j] = W2[j][i]
        w2t[idx] = W2[j * 64 + i];
    }
    for (int idx = t; idx < 3 * 64 * 64; idx += 256) {
        int mat = idx >> 12;
        int r = idx & 4095;
        int c = r >> 6, h = r & 63;           // wt[mat][c][h]
        float v = (mat == 0) ? W1[h * 130 + c]
                : (mat == 1) ? W1[h * 130 + 64 + c]
                             : Wm[h * 64 + c];
        wt[idx] = v;
    }
}

// ---------------------------------------------------------------------------
// A: per-node precompute. One matrix per block (grid = 3*512):
//    mat0: zsrc = x@W1a.T + b1 ; mat1: ztgt = x@W1b.T ; mat2: msg = relu(x@Wm.T+bm)
//    Weights read from transposed wt -> contiguous wave-uniform s_loads.
// ---------------------------------------------------------------------------
__global__ __launch_bounds__(256) void precompute_k(
    const float* __restrict__ x, const float* __restrict__ wt,
    const float* __restrict__ b1, const float* __restrict__ bm,
    float* __restrict__ zsrc, float* __restrict__ ztgt, float* __restrict__ msg)
{
    __shared__ float xt[64][65];   // xt[c][node]
    const int t = threadIdx.x;
    const int tile = blockIdx.x & 511;
    const int mat = blockIdx.x >> 9;
    const int n0 = tile * 64;
    const int b = n0 >> 14;
    const int nl0 = n0 & (NNODES - 1);
    const float* xb = x + (size_t)b * 64 * NNODES + nl0;

    #pragma unroll
    for (int rep = 0; rep < 16; ++rep) {
        int idx = rep * 256 + t;
        xt[idx >> 6][idx & 63] = xb[(size_t)(idx >> 6) * NNODES + (idx & 63)];
    }
    __syncthreads();

    const int lane = t & 63;   // node within tile
    const int wq = t >> 6;     // h-quarter (wave-uniform)
    const float* wbase = wt + mat * 4096 + wq * 16;   // wbase[c*64 + m]

    float acc[16];
    #pragma unroll
    for (int m = 0; m < 16; ++m) acc[m] = 0.f;

    #pragma unroll 4
    for (int c = 0; c < 64; ++c) {
        float xv = xt[c][lane];
        #pragma unroll
        for (int m = 0; m < 16; ++m)
            acc[m] = fmaf(xv, wbase[c * 64 + m], acc[m]);
    }

    #pragma unroll
    for (int m = 0; m < 16; ++m) {
        if (mat == 0) acc[m] += b1[wq * 16 + m];
        if (mat == 2) acc[m] = fmaxf(acc[m] + bm[wq * 16 + m], 0.f);
    }

    float* dst = (mat == 0) ? zsrc : (mat == 1) ? ztgt : msg;
    float* o = dst + (size_t)(n0 + lane) * 64 + wq * 16;
    #pragma unroll
    for (int q = 0; q < 4; ++q)
        ((float4*)o)[q] = make_float4(acc[4 * q + 0], acc[4 * q + 1],
                                      acc[4 * q + 2], acc[4 * q + 3]);
}

// ---------------------------------------------------------------------------
// B: scorer, 2 edges per thread (k and k+12 of the same node): za loaded once,
//    every wave-uniform w2t s_load shared by two independent FMA chains.
// ---------------------------------------------------------------------------
__global__ __launch_bounds__(256, 4) void score_k(
    const float* __restrict__ zsrc, const float* __restrict__ ztgt,
    const float* __restrict__ zpos, const float* __restrict__ w2t,
    const float* __restrict__ b2, const float* __restrict__ W3,
    const float* __restrict__ b3, float* __restrict__ scores)
{
    const int t = threadIdx.x;
    const int gid = blockIdx.x * 256 + t;   // 0 .. 393215
    const int n = (int)(((unsigned long long)gid * 0xAAAAAAABull) >> 35); // gid/12
    const int k0 = gid - n * 12;
    const int k1 = k0 + 12;
    const int b = n >> 14;
    const int nl = n & (NNODES - 1);
    const int yy = nl >> 7, xx = nl & 127;

    int nb[2];
    #pragma unroll
    for (int e = 0; e < 2; ++e) {
        int k = e ? k1 : k0;
        int kk = k + (k >= 12 ? 1 : 0);
        int q5 = (kk * 52) >> 8;
        int dy = q5 - 2, dx = kk - 5 * q5 - 2;
        int ny = min(max(yy + dy, 0), 127);
        int nx = min(max(xx + dx, 0), 127);
        nb[e] = (b << 14) + (ny << 7) + nx;
    }

    const float4* za  = (const float4*)(zsrc + (size_t)n * 64);
    const float4* zb0 = (const float4*)(ztgt + (size_t)nb[0] * 64);
    const float4* zb1 = (const float4*)(ztgt + (size_t)nb[1] * 64);
    const float4* zp0 = (const float4*)(zpos + k0 * 64);
    const float4* zp1 = (const float4*)(zpos + k1 * 64);

    float acc0[32], acc1[32];
    #pragma unroll
    for (int j = 0; j < 32; ++j) { acc0[j] = 0.f; acc1[j] = 0.f; }

    #pragma unroll 2
    for (int i4 = 0; i4 < 16; ++i4) {
        float4 a  = za[i4];
        float4 t0 = zb0[i4], p0 = zp0[i4];
        float4 t1 = zb1[i4], p1 = zp1[i4];
        float h0[4], h1[4];
        h0[0] = fmaxf(a.x + t0.x + p0.x, 0.f);  h1[0] = fmaxf(a.x + t1.x + p1.x, 0.f);
        h0[1] = fmaxf(a.y + t0.y + p0.y, 0.f);  h1[1] = fmaxf(a.y + t1.y + p1.y, 0.f);
        h0[2] = fmaxf(a.z + t0.z + p0.z, 0.f);  h1[2] = fmaxf(a.z + t1.z + p1.z, 0.f);
        h0[3] = fmaxf(a.w + t0.w + p0.w, 0.f);  h1[3] = fmaxf(a.w + t1.w + p1.w, 0.f);
        #pragma unroll
        for (int c = 0; c < 4; ++c) {
            const float* wrow = w2t + (i4 * 4 + c) * 32;   // uniform -> s_load
            #pragma unroll
            for (int j = 0; j < 32; ++j) {
                float wv = wrow[j];
                acc0[j] = fmaf(h0[c], wv, acc0[j]);
                acc1[j] = fmaf(h1[c], wv, acc1[j]);
            }
        }
    }

    float s0 = b3[0], s1 = b3[0];
    #pragma unroll
    for (int j = 0; j < 32; ++j) {
        float bj = b2[j], wj = W3[j];
        s0 = fmaf(fmaxf(acc0[j] + bj, 0.f), wj, s0);
        s1 = fmaf(fmaxf(acc1[j] + bj, 0.f), wj, s1);
    }
    scores[n * 24 + k0] = 1.f / (1.f + expf(-s0));
    scores[n * 24 + k1] = 1.f / (1.f + expf(-s1));
}

// ---------------------------------------------------------------------------
// C: per-node rank/mask/weights + weighted msg aggregation + Wo + residual.
//    32 nodes per block. Stable rank matches lax.top_k tie semantics.
// ---------------------------------------------------------------------------
__global__ __launch_bounds__(256) void agg_k(
    const float* __restrict__ x, const float* __restrict__ scores,
    const float* __restrict__ msg, const float* __restrict__ Wo,
    const float* __restrict__ bo, const float* __restrict__ thrp,
    float* __restrict__ out)
{
    __shared__ float sc[768];
    __shared__ float wl[768];
    __shared__ float sumw[32];
    __shared__ float aggL[32][64];
    __shared__ float ot[64][33];

    const int t = threadIdx.x;
    const int n0 = blockIdx.x * 32;
    const int b = n0 >> 14;
    const int nl0 = n0 & (NNODES - 1);
    const float thr_v = 1.f / (1.f + expf(-thrp[0]));

    #pragma unroll
    for (int rep = 0; rep < 3; ++rep)
        sc[rep * 256 + t] = scores[(size_t)n0 * 24 + rep * 256 + t];
    __syncthreads();

    // edge weights
    #pragma unroll
    for (int rep = 0; rep < 3; ++rep) {
        int e = rep * 256 + t;
        int nl = (int)(((unsigned)(e >> 3) * 171u) >> 9);   // e/24 for e<768
        int k = e - nl * 24;
        float s_e = sc[e];
        int rank = 0, cnt = 0;
        #pragma unroll
        for (int j = 0; j < 24; ++j) {
            float sj = sc[nl * 24 + j];
            rank += (sj > s_e || (sj == s_e && j < k)) ? 1 : 0;
            cnt  += (sj >= thr_v) ? 1 : 0;
        }
        bool mask = (cnt > 8) ? (rank < 8)
                  : ((cnt < 3) ? (rank < 3) : (s_e >= thr_v));
        float keep = 1.f / (1.f + expf(-(s_e - thr_v) * 10.f));
        wl[e] = mask ? s_e * keep : 0.f;
    }
    __syncthreads();

    if (t < 32) {
        float s = 0.f;
        #pragma unroll
        for (int k = 0; k < 24; ++k) s += wl[t * 24 + k];
        sumw[t] = s + 1e-6f;
    }
    __syncthreads();

    const int lane = t & 63;
    const int g4 = t >> 6;

    // weighted neighbor-message aggregation (msg rows coalesced 256B)
    #pragma unroll
    for (int it = 0; it < 8; ++it) {
        int nl = g4 + it * 4;
        int nn = nl0 + nl;
        int yy = nn >> 7, xx = nn & 127;
        float acc = 0.f;
        #pragma unroll
        for (int k = 0; k < 24; ++k) {
            int kk = k + (k >= 12 ? 1 : 0);
            int q5 = (kk * 52) >> 8;
            int dy = q5 - 2, dx = kk - 5 * q5 - 2;
            int ny = min(max(yy + dy, 0), 127);
            int nx = min(max(xx + dx, 0), 127);
            int nb = (b << 14) + (ny << 7) + nx;
            acc = fmaf(wl[nl * 24 + k], msg[(size_t)nb * 64 + lane], acc);
        }
        aggL[nl][lane] = acc / sumw[nl];
    }

    // Wo row for this lane's output channel, kept in registers (L1-resident)
    float4 wo[16];
    #pragma unroll
    for (int c4 = 0; c4 < 16; ++c4) wo[c4] = ((const float4*)Wo)[lane * 16 + c4];
    __syncthreads();

    // out = x + agg @ Wo.T + bo
    #pragma unroll
    for (int it = 0; it < 8; ++it) {
        int nl = g4 + it * 4;
        const float4* ar = (const float4*)aggL[nl];
        float a0 = 0.f, a1 = 0.f, a2 = 0.f, a3 = 0.f;
        #pragma unroll
        for (int c4 = 0; c4 < 16; ++c4) {
            float4 wv = wo[c4];
            float4 av = ar[c4];
            a0 = fmaf(av.x, wv.x, a0);
            a1 = fmaf(av.y, wv.y, a1);
            a2 = fmaf(av.z, wv.z, a2);
            a3 = fmaf(av.w, wv.w, a3);
        }
        float v = (a0 + a1) + (a2 + a3) + bo[lane]
                + x[(size_t)b * 64 * NNODES + (size_t)lane * NNODES + nl0 + nl];
        ot[lane][nl] = v;
    }
    __syncthreads();

    // coalesced float4 stores (128B per o-row per block)
    #pragma unroll
    for (int rep = 0; rep < 2; ++rep) {
        int idx = rep * 256 + t;
        int o = idx >> 3, p = idx & 7;
        float4 v = make_float4(ot[o][4 * p + 0], ot[o][4 * p + 1],
                               ot[o][4 * p + 2], ot[o][4 * p + 3]);
        *(float4*)(out + (size_t)b * 64 * NNODES + (size_t)o * NNODES + nl0 + 4 * p) = v;
    }
}

// ---------------------------------------------------------------------------
extern "C" void kernel_launch(void* const* d_in, const int* in_sizes, int n_in,
                              void* d_out, int out_size, void* d_ws, size_t ws_size,
                              hipStream_t stream)
{
    const float* x   = (const float*)d_in[0];
    const float* W1  = (const float*)d_in[1];
    const float* b1  = (const float*)d_in[2];
    const float* W2  = (const float*)d_in[3];
    const float* b2  = (const float*)d_in[4];
    const float* W3  = (const float*)d_in[5];
    const float* b3  = (const float*)d_in[6];
    const float* thr = (const float*)d_in[7];
    const float* Wm  = (const float*)d_in[8];
    const float* bm  = (const float*)d_in[9];
    const float* Wo  = (const float*)d_in[10];
    const float* bo  = (const float*)d_in[11];
    float* out = (float*)d_out;
    float* ws  = (float*)d_ws;

    // ws layout (floats): zsrc[2M] ztgt[2M] msg[2M] scores[768K] zpos[1536]
    //                     w2t[2048] wt[12288]
    float* zsrc   = ws;
    float* ztgt   = ws + 2097152;
    float* msg    = ws + 4194304;
    float* scores = ws + 6291456;
    float* zpos   = ws + 7077888;
    float* w2t    = ws + 7079424;
    float* wt     = ws + 7081472;

    hipLaunchKernelGGL(aux_k, dim3(1), dim3(256), 0, stream, W1, W2, Wm, zpos, w2t, wt);
    hipLaunchKernelGGL(precompute_k, dim3(1536), dim3(256), 0, stream,
                       x, wt, b1, bm, zsrc, ztgt, msg);
    hipLaunchKernelGGL(score_k, dim3(1536), dim3(256), 0, stream,
                       zsrc, ztgt, zpos, w2t, b2, W3, b3, scores);
    hipLaunchKernelGGL(agg_k, dim3(1024), dim3(256), 0, stream,
                       x, scores, msg, Wo, bo, thr, out);
}

// Round 4
// 124.569 us; speedup vs baseline: 1.2026x; 1.2026x over previous
//
#include <hip/hip_runtime.h>
#include <hip/hip_bf16.h>
#include <math.h>

// Problem constants (B,C,H,W) = (2,64,128,128), R=2 -> K=24 neighbors.
#define NNODES 16384            // H*W
#define KE 24

typedef float f32x4 __attribute__((ext_vector_type(4)));
typedef short bf16x8 __attribute__((ext_vector_type(8)));

static __device__ __forceinline__ unsigned short f2bf(float f) {
    union { float f; unsigned u; } x; x.f = f;
    unsigned r = x.u + 0x7FFFu + ((x.u >> 16) & 1u);   // RNE
    return (unsigned short)(r >> 16);
}
static __device__ __forceinline__ float bf2f(unsigned short b) {
    union { unsigned u; float f; } x; x.u = ((unsigned)b) << 16;
    return x.f;
}

// ---------------------------------------------------------------------------
// aux: zpos[k][h] table + W2T [64][32] + wt[mat][c][h] transposed weights
// ---------------------------------------------------------------------------
__global__ void aux_k(const float* __restrict__ W1, const float* __restrict__ W2,
                      const float* __restrict__ Wm,
                      float* __restrict__ zpos, float* __restrict__ w2t,
                      float* __restrict__ wt)
{
    int t = threadIdx.x;
    for (int idx = t; idx < KE * 64; idx += 256) {
        int k = idx >> 6, h = idx & 63;
        int kk = k + (k >= 12 ? 1 : 0);       // skip center of 5x5
        int q5 = (kk * 52) >> 8;              // kk/5 for kk<25
        int dy = q5 - 2;
        int dx = kk - 5 * q5 - 2;
        zpos[idx] = W1[h * 130 + 128] * (dx * 0.5f)
                  + W1[h * 130 + 129] * (dy * 0.5f);
    }
    for (int idx = t; idx < 64 * 32; idx += 256) {
        int i = idx >> 5, j = idx & 31;       // w2t[c][j] = W2[j][c]
        w2t[idx] = W2[j * 64 + i];
    }
    for (int idx = t; idx < 3 * 64 * 64; idx += 256) {
        int mat = idx >> 12;
        int r = idx & 4095;
        int c = r >> 6, h = r & 63;           // wt[mat][c][h]
        float v = (mat == 0) ? W1[h * 130 + c]
                : (mat == 1) ? W1[h * 130 + 64 + c]
                             : Wm[h * 64 + c];
        wt[idx] = v;
    }
}

// ---------------------------------------------------------------------------
// A: register-blocked LDS GEMM. Block = 128 threads, one mat x 64h x 128 nodes.
//    Thread owns 8h x 8n (64 acc). Per c: 4 LDS b128 feed 64 FMAs -> VALU-bound.
// ---------------------------------------------------------------------------
__global__ __launch_bounds__(128) void precompute_k(
    const float* __restrict__ x, const float* __restrict__ wt,
    const float* __restrict__ b1, const float* __restrict__ bm,
    float* __restrict__ zsrc, float* __restrict__ ztgt, float* __restrict__ msg)
{
    __shared__ float xt[64][128];   // [c][node]  32 KB
    __shared__ float wl[64][64];    // [c][h]     16 KB
    const int t = threadIdx.x;
    const int mat = blockIdx.x >> 8;        // grid = 3*256
    const int tile = blockIdx.x & 255;
    const int n0 = tile * 128;
    const int b = n0 >> 14;
    const int nl0 = n0 & (NNODES - 1);
    const float* xb = x + (size_t)b * 64 * NNODES + nl0;

    #pragma unroll
    for (int r = 0; r < 16; ++r) {
        int idx = r * 128 + t;              // 2048 float4s
        int c = idx >> 5, j4 = idx & 31;
        float4 v = *(const float4*)(xb + (size_t)c * NNODES + j4 * 4);
        *(float4*)&xt[c][j4 * 4] = v;
    }
    #pragma unroll
    for (int r = 0; r < 8; ++r) {
        int idx = r * 128 + t;              // 1024 float4s
        int c = idx >> 4, h4 = idx & 15;
        *(float4*)&wl[c][h4 * 4] = *(const float4*)(wt + mat * 4096 + c * 64 + h4 * 4);
    }
    __syncthreads();

    const int i = t >> 4;   // h-octet: h = i*8..i*8+7
    const int j = t & 15;   // node-group: nodes j*8..j*8+7

    float acc[8][8];
    #pragma unroll
    for (int a = 0; a < 8; ++a)
        #pragma unroll
        for (int bb = 0; bb < 8; ++bb) acc[a][bb] = 0.f;

    #pragma unroll 4
    for (int c = 0; c < 64; ++c) {
        float4 w0 = *(const float4*)&wl[c][i * 8];
        float4 w1 = *(const float4*)&wl[c][i * 8 + 4];
        float4 x0 = *(const float4*)&xt[c][j * 8];
        float4 x1 = *(const float4*)&xt[c][j * 8 + 4];
        float wv[8] = {w0.x, w0.y, w0.z, w0.w, w1.x, w1.y, w1.z, w1.w};
        float xv[8] = {x0.x, x0.y, x0.z, x0.w, x1.x, x1.y, x1.z, x1.w};
        #pragma unroll
        for (int a = 0; a < 8; ++a)
            #pragma unroll
            for (int bb = 0; bb < 8; ++bb)
                acc[a][bb] = fmaf(wv[a], xv[bb], acc[a][bb]);
    }

    #pragma unroll
    for (int a = 0; a < 8; ++a) {
        float bv = (mat == 0) ? b1[i * 8 + a] : (mat == 2) ? bm[i * 8 + a] : 0.f;
        #pragma unroll
        for (int bb = 0; bb < 8; ++bb) {
            float v = acc[a][bb] + bv;
            acc[a][bb] = (mat == 2) ? fmaxf(v, 0.f) : v;
        }
    }

    float* dst = (mat == 0) ? zsrc : (mat == 1) ? ztgt : msg;
    #pragma unroll
    for (int nn = 0; nn < 8; ++nn) {
        float* o = dst + (size_t)(n0 + j * 8 + nn) * 64 + i * 8;
        *(float4*)o       = make_float4(acc[0][nn], acc[1][nn], acc[2][nn], acc[3][nn]);
        *(float4*)(o + 4) = make_float4(acc[4][nn], acc[5][nn], acc[6][nn], acc[7][nn]);
    }
}

// ---------------------------------------------------------------------------
// B: scorer via split-bf16 MFMA (hi/lo decomposition ~ fp32 precision).
//    One wave = one node (24 edges = 2 M-tiles of 16x16x32), 8 nodes/wave.
//    W2T stationary in per-lane B-fragments; 24 MFMAs + shfl-reduce epilogue.
// ---------------------------------------------------------------------------
__global__ __launch_bounds__(256) void score_k(
    const float* __restrict__ zsrc, const float* __restrict__ ztgt,
    const float* __restrict__ zpos, const float* __restrict__ w2t,
    const float* __restrict__ b2, const float* __restrict__ W3,
    const float* __restrict__ b3, float* __restrict__ scores)
{
    const int t = threadIdx.x;
    const int l = t & 63;
    const int lcol = l & 15;    // M-row / N-col selector
    const int lgrp = l >> 4;    // K-block selector
    const int wave = blockIdx.x * 4 + (t >> 6);

    // B fragments: B[k][n] = w2t[k][n], n = nt*16+lcol, k = kt*32+lgrp*8+i
    bf16x8 Bhi[2][2], Blo[2][2];
    #pragma unroll
    for (int nt = 0; nt < 2; ++nt)
        #pragma unroll
        for (int kt = 0; kt < 2; ++kt)
            #pragma unroll
            for (int i = 0; i < 8; ++i) {
                float v = w2t[(kt * 32 + lgrp * 8 + i) * 32 + nt * 16 + lcol];
                unsigned short hi = f2bf(v);
                unsigned short lo = f2bf(v - bf2f(hi));
                Bhi[nt][kt][i] = (short)hi;
                Blo[nt][kt][i] = (short)lo;
            }

    const float b2v0 = b2[lcol], b2v1 = b2[lcol + 16];
    const float w3v0 = W3[lcol], w3v1 = W3[lcol + 16];
    const float b3s = b3[0];

    for (int rep = 0; rep < 8; ++rep) {
        const int n = wave * 8 + rep;
        const int b = n >> 14;
        const int nl = n & (NNODES - 1);
        const int yy = nl >> 7, xx = nl & 127;

        f32x4 acc[2][2];
        #pragma unroll
        for (int mt = 0; mt < 2; ++mt)
            #pragma unroll
            for (int nt = 0; nt < 2; ++nt)
                acc[mt][nt] = (f32x4)0.f;

        #pragma unroll
        for (int Mt = 0; Mt < 2; ++Mt) {
            const int k_e = Mt * 16 + lcol;          // edge (row) this lane feeds
            const int ks = min(k_e, 23);
            const bool valid = (k_e < 24);
            const int kk = ks + (ks >= 12 ? 1 : 0);
            const int q5 = (kk * 52) >> 8;
            const int dy = q5 - 2, dx = kk - 5 * q5 - 2;
            const int ny = min(max(yy + dy, 0), 127);
            const int nx = min(max(xx + dx, 0), 127);
            const int nbn = (b << 14) + (ny << 7) + nx;

            #pragma unroll
            for (int kt = 0; kt < 2; ++kt) {
                const int c0 = kt * 32 + lgrp * 8;
                float4 a0 = *(const float4*)(zsrc + (size_t)n * 64 + c0);
                float4 a1 = *(const float4*)(zsrc + (size_t)n * 64 + c0 + 4);
                float4 t0 = *(const float4*)(ztgt + (size_t)nbn * 64 + c0);
                float4 t1 = *(const float4*)(ztgt + (size_t)nbn * 64 + c0 + 4);
                float4 p0 = *(const float4*)(zpos + ks * 64 + c0);
                float4 p1 = *(const float4*)(zpos + ks * 64 + c0 + 4);
                float v[8];
                v[0] = fmaxf(a0.x + t0.x + p0.x, 0.f);
                v[1] = fmaxf(a0.y + t0.y + p0.y, 0.f);
                v[2] = fmaxf(a0.z + t0.z + p0.z, 0.f);
                v[3] = fmaxf(a0.w + t0.w + p0.w, 0.f);
                v[4] = fmaxf(a1.x + t1.x + p1.x, 0.f);
                v[5] = fmaxf(a1.y + t1.y + p1.y, 0.f);
                v[6] = fmaxf(a1.z + t1.z + p1.z, 0.f);
                v[7] = fmaxf(a1.w + t1.w + p1.w, 0.f);
                bf16x8 Ahi, Alo;
                #pragma unroll
                for (int i = 0; i < 8; ++i) {
                    float vv = valid ? v[i] : 0.f;
                    unsigned short hi = f2bf(vv);
                    Ahi[i] = (short)hi;
                    Alo[i] = (short)f2bf(vv - bf2f(hi));
                }
                #pragma unroll
                for (int nt = 0; nt < 2; ++nt) {
                    acc[Mt][nt] = __builtin_amdgcn_mfma_f32_16x16x32_bf16(
                        Ahi, Bhi[nt][kt], acc[Mt][nt], 0, 0, 0);
                    acc[Mt][nt] = __builtin_amdgcn_mfma_f32_16x16x32_bf16(
                        Alo, Bhi[nt][kt], acc[Mt][nt], 0, 0, 0);
                    acc[Mt][nt] = __builtin_amdgcn_mfma_f32_16x16x32_bf16(
                        Ahi, Blo[nt][kt], acc[Mt][nt], 0, 0, 0);
                }
            }
        }

        // epilogue: h2 = relu(acc + b2); spre = sum_j h2*W3; reduce over 16 j-lanes
        #pragma unroll
        for (int Mt = 0; Mt < 2; ++Mt)
            #pragma unroll
            for (int q = 0; q < 4; ++q) {
                float s = fmaxf(acc[Mt][0][q] + b2v0, 0.f) * w3v0
                        + fmaxf(acc[Mt][1][q] + b2v1, 0.f) * w3v1;
                s += __shfl_xor(s, 1);
                s += __shfl_xor(s, 2);
                s += __shfl_xor(s, 4);
                s += __shfl_xor(s, 8);
                float sig = 1.f / (1.f + expf(-(s + b3s)));
                int ke = Mt * 16 + lgrp * 4 + q;     // C row = (lane>>4)*4 + reg
                if (lcol == 0 && ke < 24)
                    scores[(size_t)n * 24 + ke] = sig;
            }
    }
}

// ---------------------------------------------------------------------------
// C: per-node rank/mask/weights + weighted msg aggregation + Wo + residual.
// ---------------------------------------------------------------------------
__global__ __launch_bounds__(256) void agg_k(
    const float* __restrict__ x, const float* __restrict__ scores,
    const float* __restrict__ msg, const float* __restrict__ Wo,
    const float* __restrict__ bo, const float* __restrict__ thrp,
    float* __restrict__ out)
{
    __shared__ float sc[768];
    __shared__ float wl[768];
    __shared__ float sumw[32];
    __shared__ float aggL[32][64];
    __shared__ float ot[64][33];

    const int t = threadIdx.x;
    const int n0 = blockIdx.x * 32;
    const int b = n0 >> 14;
    const int nl0 = n0 & (NNODES - 1);
    const float thr_v = 1.f / (1.f + expf(-thrp[0]));

    #pragma unroll
    for (int rep = 0; rep < 3; ++rep)
        sc[rep * 256 + t] = scores[(size_t)n0 * 24 + rep * 256 + t];
    __syncthreads();

    #pragma unroll
    for (int rep = 0; rep < 3; ++rep) {
        int e = rep * 256 + t;
        int nl = (int)(((unsigned)(e >> 3) * 171u) >> 9);   // e/24 for e<768
        int k = e - nl * 24;
        float s_e = sc[e];
        int rank = 0, cnt = 0;
        #pragma unroll
        for (int j = 0; j < 24; ++j) {
            float sj = sc[nl * 24 + j];
            rank += (sj > s_e || (sj == s_e && j < k)) ? 1 : 0;
            cnt  += (sj >= thr_v) ? 1 : 0;
        }
        bool mask = (cnt > 8) ? (rank < 8)
                  : ((cnt < 3) ? (rank < 3) : (s_e >= thr_v));
        float keep = 1.f / (1.f + expf(-(s_e - thr_v) * 10.f));
        wl[e] = mask ? s_e * keep : 0.f;
    }
    __syncthreads();

    if (t < 32) {
        float s = 0.f;
        #pragma unroll
        for (int k = 0; k < 24; ++k) s += wl[t * 24 + k];
        sumw[t] = s + 1e-6f;
    }
    __syncthreads();

    const int lane = t & 63;
    const int g4 = t >> 6;

    #pragma unroll
    for (int it = 0; it < 8; ++it) {
        int nl = g4 + it * 4;
        int nn = nl0 + nl;
        int yy = nn >> 7, xx = nn & 127;
        float acc = 0.f;
        #pragma unroll
        for (int k = 0; k < 24; ++k) {
            int kk = k + (k >= 12 ? 1 : 0);
            int q5 = (kk * 52) >> 8;
            int dy = q5 - 2, dx = kk - 5 * q5 - 2;
            int ny = min(max(yy + dy, 0), 127);
            int nx = min(max(xx + dx, 0), 127);
            int nb = (b << 14) + (ny << 7) + nx;
            acc = fmaf(wl[nl * 24 + k], msg[(size_t)nb * 64 + lane], acc);
        }
        aggL[nl][lane] = acc / sumw[nl];
    }

    float4 wo[16];
    #pragma unroll
    for (int c4 = 0; c4 < 16; ++c4) wo[c4] = ((const float4*)Wo)[lane * 16 + c4];
    __syncthreads();

    #pragma unroll
    for (int it = 0; it < 8; ++it) {
        int nl = g4 + it * 4;
        const float4* ar = (const float4*)aggL[nl];
        float a0 = 0.f, a1 = 0.f, a2 = 0.f, a3 = 0.f;
        #pragma unroll
        for (int c4 = 0; c4 < 16; ++c4) {
            float4 wv = wo[c4];
            float4 av = ar[c4];
            a0 = fmaf(av.x, wv.x, a0);
            a1 = fmaf(av.y, wv.y, a1);
            a2 = fmaf(av.z, wv.z, a2);
            a3 = fmaf(av.w, wv.w, a3);
        }
        float v = (a0 + a1) + (a2 + a3) + bo[lane]
                + x[(size_t)b * 64 * NNODES + (size_t)lane * NNODES + nl0 + nl];
        ot[lane][nl] = v;
    }
    __syncthreads();

    #pragma unroll
    for (int rep = 0; rep < 2; ++rep) {
        int idx = rep * 256 + t;
        int o = idx >> 3, p = idx & 7;
        float4 v = make_float4(ot[o][4 * p + 0], ot[o][4 * p + 1],
                               ot[o][4 * p + 2], ot[o][4 * p + 3]);
        *(float4*)(out + (size_t)b * 64 * NNODES + (size_t)o * NNODES + nl0 + 4 * p) = v;
    }
}

// ---------------------------------------------------------------------------
extern "C" void kernel_launch(void* const* d_in, const int* in_sizes, int n_in,
                              void* d_out, int out_size, void* d_ws, size_t ws_size,
                              hipStream_t stream)
{
    const float* x   = (const float*)d_in[0];
    const float* W1  = (const float*)d_in[1];
    const float* b1  = (const float*)d_in[2];
    const float* W2  = (const float*)d_in[3];
    const float* b2  = (const float*)d_in[4];
    const float* W3  = (const float*)d_in[5];
    const float* b3  = (const float*)d_in[6];
    const float* thr = (const float*)d_in[7];
    const float* Wm  = (const float*)d_in[8];
    const float* bm  = (const float*)d_in[9];
    const float* Wo  = (const float*)d_in[10];
    const float* bo  = (const float*)d_in[11];
    float* out = (float*)d_out;
    float* ws  = (float*)d_ws;

    // ws layout (floats): zsrc[2M] ztgt[2M] msg[2M] scores[768K] zpos[1536]
    //                     w2t[2048] wt[12288]
    float* zsrc   = ws;
    float* ztgt   = ws + 2097152;
    float* msg    = ws + 4194304;
    float* scores = ws + 6291456;
    float* zpos   = ws + 7077888;
    float* w2t    = ws + 7079424;
    float* wt     = ws + 7081472;

    hipLaunchKernelGGL(aux_k, dim3(1), dim3(256), 0, stream, W1, W2, Wm, zpos, w2t, wt);
    hipLaunchKernelGGL(precompute_k, dim3(768), dim3(128), 0, stream,
                       x, wt, b1, bm, zsrc, ztgt, msg);
    hipLaunchKernelGGL(score_k, dim3(1024), dim3(256), 0, stream,
                       zsrc, ztgt, zpos, w2t, b2, W3, b3, scores);
    hipLaunchKernelGGL(agg_k, dim3(1024), dim3(256), 0, stream,
                       x, scores, msg, Wo, bo, thr, out);
}

// Round 5
// 119.089 us; speedup vs baseline: 1.2579x; 1.0460x over previous
//
#include <hip/hip_runtime.h>
#include <hip/hip_bf16.h>
#include <math.h>

// Problem constants (B,C,H,W) = (2,64,128,128), R=2 -> K=24 neighbors.
#define NNODES 16384            // H*W
#define KE 24

typedef float f32x4 __attribute__((ext_vector_type(4)));
typedef short bf16x8 __attribute__((ext_vector_type(8)));
typedef unsigned u32x4 __attribute__((ext_vector_type(4)));

union fragcast { u32x4 u; bf16x8 b; };

// Exact 3-way truncation split: v == hi + lo + lo2 (all bf16-representable),
// 24 = 8+8+8 significant bits. Returns the three parts as fp32 bit patterns
// with low 16 bits zero (the bf16 value is the top half).
static __device__ __forceinline__ void split3(float v, unsigned& uhi,
                                              unsigned& ulo, unsigned& ulo2) {
    union { float f; unsigned u; } a; a.f = v;
    uhi = a.u & 0xFFFF0000u;
    union { unsigned u; float f; } h; h.u = uhi;
    float r1 = v - h.f;                      // exact
    union { float f; unsigned u; } b; b.f = r1;
    ulo = b.u & 0xFFFF0000u;
    union { unsigned u; float f; } l; l.u = ulo;
    float r2 = r1 - l.f;                     // exact, <= 8 sig bits
    union { float f; unsigned u; } c; c.f = r2;
    ulo2 = c.u & 0xFFFF0000u;                // exact (no bits lost)
}

// ---------------------------------------------------------------------------
// aux: zpos[k][h] table + wt[mat][c][h] transposed weights
// ---------------------------------------------------------------------------
__global__ void aux_k(const float* __restrict__ W1, const float* __restrict__ Wm,
                      float* __restrict__ zpos, float* __restrict__ wt)
{
    int t = threadIdx.x;
    for (int idx = t; idx < KE * 64; idx += 256) {
        int k = idx >> 6, h = idx & 63;
        int kk = k + (k >= 12 ? 1 : 0);       // skip center of 5x5
        int q5 = (kk * 52) >> 8;              // kk/5 for kk<25
        int dy = q5 - 2;
        int dx = kk - 5 * q5 - 2;
        zpos[idx] = W1[h * 130 + 128] * (dx * 0.5f)
                  + W1[h * 130 + 129] * (dy * 0.5f);
    }
    for (int idx = t; idx < 3 * 64 * 64; idx += 256) {
        int mat = idx >> 12;
        int r = idx & 4095;
        int c = r >> 6, h = r & 63;           // wt[mat][c][h]
        float v = (mat == 0) ? W1[h * 130 + c]
                : (mat == 1) ? W1[h * 130 + 64 + c]
                             : Wm[h * 64 + c];
        wt[idx] = v;
    }
}

// ---------------------------------------------------------------------------
// A: register-blocked LDS GEMM. Block = 128 threads, one mat x 64h x 128 nodes.
// ---------------------------------------------------------------------------
__global__ __launch_bounds__(128) void precompute_k(
    const float* __restrict__ x, const float* __restrict__ wt,
    const float* __restrict__ b1, const float* __restrict__ bm,
    float* __restrict__ zsrc, float* __restrict__ ztgt, float* __restrict__ msg)
{
    __shared__ float xt[64][128];   // [c][node]  32 KB
    __shared__ float wl[64][64];    // [c][h]     16 KB
    const int t = threadIdx.x;
    const int mat = blockIdx.x >> 8;        // grid = 3*256
    const int tile = blockIdx.x & 255;
    const int n0 = tile * 128;
    const int b = n0 >> 14;
    const int nl0 = n0 & (NNODES - 1);
    const float* xb = x + (size_t)b * 64 * NNODES + nl0;

    #pragma unroll
    for (int r = 0; r < 16; ++r) {
        int idx = r * 128 + t;              // 2048 float4s
        int c = idx >> 5, j4 = idx & 31;
        float4 v = *(const float4*)(xb + (size_t)c * NNODES + j4 * 4);
        *(float4*)&xt[c][j4 * 4] = v;
    }
    #pragma unroll
    for (int r = 0; r < 8; ++r) {
        int idx = r * 128 + t;              // 1024 float4s
        int c = idx >> 4, h4 = idx & 15;
        *(float4*)&wl[c][h4 * 4] = *(const float4*)(wt + mat * 4096 + c * 64 + h4 * 4);
    }
    __syncthreads();

    const int i = t >> 4;   // h-octet
    const int j = t & 15;   // node-group

    float acc[8][8];
    #pragma unroll
    for (int a = 0; a < 8; ++a)
        #pragma unroll
        for (int bb = 0; bb < 8; ++bb) acc[a][bb] = 0.f;

    #pragma unroll 4
    for (int c = 0; c < 64; ++c) {
        float4 w0 = *(const float4*)&wl[c][i * 8];
        float4 w1 = *(const float4*)&wl[c][i * 8 + 4];
        float4 x0 = *(const float4*)&xt[c][j * 8];
        float4 x1 = *(const float4*)&xt[c][j * 8 + 4];
        float wv[8] = {w0.x, w0.y, w0.z, w0.w, w1.x, w1.y, w1.z, w1.w};
        float xv[8] = {x0.x, x0.y, x0.z, x0.w, x1.x, x1.y, x1.z, x1.w};
        #pragma unroll
        for (int a = 0; a < 8; ++a)
            #pragma unroll
            for (int bb = 0; bb < 8; ++bb)
                acc[a][bb] = fmaf(wv[a], xv[bb], acc[a][bb]);
    }

    #pragma unroll
    for (int a = 0; a < 8; ++a) {
        float bv = (mat == 0) ? b1[i * 8 + a] : (mat == 2) ? bm[i * 8 + a] : 0.f;
        #pragma unroll
        for (int bb = 0; bb < 8; ++bb) {
            float v = acc[a][bb] + bv;
            acc[a][bb] = (mat == 2) ? fmaxf(v, 0.f) : v;
        }
    }

    float* dst = (mat == 0) ? zsrc : (mat == 1) ? ztgt : msg;
    #pragma unroll
    for (int nn = 0; nn < 8; ++nn) {
        float* o = dst + (size_t)(n0 + j * 8 + nn) * 64 + i * 8;
        *(float4*)o       = make_float4(acc[0][nn], acc[1][nn], acc[2][nn], acc[3][nn]);
        *(float4*)(o + 4) = make_float4(acc[4][nn], acc[5][nn], acc[6][nn], acc[7][nn]);
    }
}

// ---------------------------------------------------------------------------
// B: scorer via EXACT 3-way-split bf16 MFMA (fp32-accurate, ~1e-7).
//    2 nodes per wave-step = 48 edges = 3 full 16-row M-tiles (no waste).
//    6 MFMA terms on 4 independent accumulator chains.
// ---------------------------------------------------------------------------
__global__ __launch_bounds__(256, 3) void score_k(
    const float* __restrict__ zsrc, const float* __restrict__ ztgt,
    const float* __restrict__ zpos, const float* __restrict__ W2,
    const float* __restrict__ b2, const float* __restrict__ W3,
    const float* __restrict__ b3, float* __restrict__ scores)
{
    const int t = threadIdx.x;
    const int l = t & 63;
    const int lcol = l & 15;    // A-row / B-col / C-col selector
    const int lgrp = l >> 4;    // K-block selector
    const int wave = blockIdx.x * 4 + (t >> 6);   // 4096 waves, 8 nodes each

    // B fragments: exact 3-way split of W2 (B[k][n] = W2[n][k])
    bf16x8 Bhi[2][2], Blo[2][2], Blo2[2][2];
    #pragma unroll
    for (int nt = 0; nt < 2; ++nt)
        #pragma unroll
        for (int kt = 0; kt < 2; ++kt) {
            fragcast fh, fl, fl2;
            #pragma unroll
            for (int d = 0; d < 4; ++d) {
                unsigned h0, l0, m0, h1, l1, m1;
                const float* wr = W2 + (size_t)(nt * 16 + lcol) * 64 + kt * 32 + lgrp * 8;
                split3(wr[2 * d],     h0, l0, m0);
                split3(wr[2 * d + 1], h1, l1, m1);
                fh.u[d]  = h1 | (h0 >> 16);
                fl.u[d]  = l1 | (l0 >> 16);
                fl2.u[d] = m1 | (m0 >> 16);
            }
            Bhi[nt][kt] = fh.b; Blo[nt][kt] = fl.b; Blo2[nt][kt] = fl2.b;
        }

    const float b2v0 = b2[lcol], b2v1 = b2[lcol + 16];
    const float w3v0 = W3[lcol], w3v1 = W3[lcol + 16];
    const float b3s = b3[0];

    for (int p = 0; p < 4; ++p) {
        const int node0 = wave * 8 + p * 2;

        #pragma unroll
        for (int Mt = 0; Mt < 3; ++Mt) {
            const int ke = Mt * 16 + lcol;           // edge index within pair, 0..47
            const int nsel = (ke >= 24) ? 1 : 0;
            const int node = node0 + nsel;
            const int k = ke - 24 * nsel;
            const int bb = node >> 14;
            const int nl = node & (NNODES - 1);
            const int yy = nl >> 7, xx = nl & 127;
            const int kk = k + (k >= 12 ? 1 : 0);
            const int q5 = (kk * 52) >> 8;
            const int dy = q5 - 2, dx = kk - 5 * q5 - 2;
            const int ny = min(max(yy + dy, 0), 127);
            const int nx = min(max(xx + dx, 0), 127);
            const int nbn = (bb << 14) + (ny << 7) + nx;

            f32x4 ac0A = {0.f, 0.f, 0.f, 0.f}, ac0B = {0.f, 0.f, 0.f, 0.f};
            f32x4 ac1A = {0.f, 0.f, 0.f, 0.f}, ac1B = {0.f, 0.f, 0.f, 0.f};

            #pragma unroll
            for (int kt = 0; kt < 2; ++kt) {
                const int c0 = kt * 32 + lgrp * 8;
                float4 a0 = *(const float4*)(zsrc + (size_t)node * 64 + c0);
                float4 a1 = *(const float4*)(zsrc + (size_t)node * 64 + c0 + 4);
                float4 t0 = *(const float4*)(ztgt + (size_t)nbn * 64 + c0);
                float4 t1 = *(const float4*)(ztgt + (size_t)nbn * 64 + c0 + 4);
                float4 p0 = *(const float4*)(zpos + k * 64 + c0);
                float4 p1 = *(const float4*)(zpos + k * 64 + c0 + 4);
                float v[8];
                v[0] = fmaxf(a0.x + t0.x + p0.x, 0.f);
                v[1] = fmaxf(a0.y + t0.y + p0.y, 0.f);
                v[2] = fmaxf(a0.z + t0.z + p0.z, 0.f);
                v[3] = fmaxf(a0.w + t0.w + p0.w, 0.f);
                v[4] = fmaxf(a1.x + t1.x + p1.x, 0.f);
                v[5] = fmaxf(a1.y + t1.y + p1.y, 0.f);
                v[6] = fmaxf(a1.z + t1.z + p1.z, 0.f);
                v[7] = fmaxf(a1.w + t1.w + p1.w, 0.f);

                fragcast Ah, Al, Al2;
                #pragma unroll
                for (int d = 0; d < 4; ++d) {
                    unsigned h0, l0, m0, h1, l1, m1;
                    split3(v[2 * d],     h0, l0, m0);
                    split3(v[2 * d + 1], h1, l1, m1);
                    Ah.u[d]  = h1 | (h0 >> 16);
                    Al.u[d]  = l1 | (l0 >> 16);
                    Al2.u[d] = m1 | (m0 >> 16);
                }

                // chain A (Bhi terms), chain B (Blo/Blo2 terms) per nt:
                ac0A = __builtin_amdgcn_mfma_f32_16x16x32_bf16(Ah.b,  Bhi[0][kt], ac0A, 0, 0, 0);
                ac1A = __builtin_amdgcn_mfma_f32_16x16x32_bf16(Ah.b,  Bhi[1][kt], ac1A, 0, 0, 0);
                ac0B = __builtin_amdgcn_mfma_f32_16x16x32_bf16(Ah.b,  Blo[0][kt], ac0B, 0, 0, 0);
                ac1B = __builtin_amdgcn_mfma_f32_16x16x32_bf16(Ah.b,  Blo[1][kt], ac1B, 0, 0, 0);
                ac0A = __builtin_amdgcn_mfma_f32_16x16x32_bf16(Al.b,  Bhi[0][kt], ac0A, 0, 0, 0);
                ac1A = __builtin_amdgcn_mfma_f32_16x16x32_bf16(Al.b,  Bhi[1][kt], ac1A, 0, 0, 0);
                ac0B = __builtin_amdgcn_mfma_f32_16x16x32_bf16(Al.b,  Blo[0][kt], ac0B, 0, 0, 0);
                ac1B = __builtin_amdgcn_mfma_f32_16x16x32_bf16(Al.b,  Blo[1][kt], ac1B, 0, 0, 0);
                ac0A = __builtin_amdgcn_mfma_f32_16x16x32_bf16(Al2.b, Bhi[0][kt], ac0A, 0, 0, 0);
                ac1A = __builtin_amdgcn_mfma_f32_16x16x32_bf16(Al2.b, Bhi[1][kt], ac1A, 0, 0, 0);
                ac0B = __builtin_amdgcn_mfma_f32_16x16x32_bf16(Ah.b,  Blo2[0][kt], ac0B, 0, 0, 0);
                ac1B = __builtin_amdgcn_mfma_f32_16x16x32_bf16(Ah.b,  Blo2[1][kt], ac1B, 0, 0, 0);
            }

            const f32x4 s0 = ac0A + ac0B;
            const f32x4 s1 = ac1A + ac1B;
            #pragma unroll
            for (int q = 0; q < 4; ++q) {
                float s = fmaxf(s0[q] + b2v0, 0.f) * w3v0
                        + fmaxf(s1[q] + b2v1, 0.f) * w3v1;
                s += __shfl_xor(s, 1);
                s += __shfl_xor(s, 2);
                s += __shfl_xor(s, 4);
                s += __shfl_xor(s, 8);
                float sig = 1.f / (1.f + expf(-(s + b3s)));
                if (lcol == 0)
                    scores[(size_t)node0 * 24 + Mt * 16 + lgrp * 4 + q] = sig;
            }
        }
    }
}

// ---------------------------------------------------------------------------
// C: per-node rank/mask/weights + weighted msg aggregation + Wo + residual.
// ---------------------------------------------------------------------------
__global__ __launch_bounds__(256) void agg_k(
    const float* __restrict__ x, const float* __restrict__ scores,
    const float* __restrict__ msg, const float* __restrict__ Wo,
    const float* __restrict__ bo, const float* __restrict__ thrp,
    float* __restrict__ out)
{
    __shared__ float sc[768];
    __shared__ float wl[768];
    __shared__ float sumw[32];
    __shared__ float aggL[32][64];
    __shared__ float ot[64][33];

    const int t = threadIdx.x;
    const int n0 = blockIdx.x * 32;
    const int b = n0 >> 14;
    const int nl0 = n0 & (NNODES - 1);
    const float thr_v = 1.f / (1.f + expf(-thrp[0]));

    #pragma unroll
    for (int rep = 0; rep < 3; ++rep)
        sc[rep * 256 + t] = scores[(size_t)n0 * 24 + rep * 256 + t];
    __syncthreads();

    #pragma unroll
    for (int rep = 0; rep < 3; ++rep) {
        int e = rep * 256 + t;
        int nl = (int)(((unsigned)(e >> 3) * 171u) >> 9);   // e/24 for e<768
        int k = e - nl * 24;
        float s_e = sc[e];
        int rank = 0, cnt = 0;
        #pragma unroll
        for (int j = 0; j < 24; ++j) {
            float sj = sc[nl * 24 + j];
            rank += (sj > s_e || (sj == s_e && j < k)) ? 1 : 0;
            cnt  += (sj >= thr_v) ? 1 : 0;
        }
        bool mask = (cnt > 8) ? (rank < 8)
                  : ((cnt < 3) ? (rank < 3) : (s_e >= thr_v));
        float keep = 1.f / (1.f + expf(-(s_e - thr_v) * 10.f));
        wl[e] = mask ? s_e * keep : 0.f;
    }
    __syncthreads();

    if (t < 32) {
        float s = 0.f;
        #pragma unroll
        for (int k = 0; k < 24; ++k) s += wl[t * 24 + k];
        sumw[t] = s + 1e-6f;
    }
    __syncthreads();

    const int lane = t & 63;
    const int g4 = t >> 6;

    #pragma unroll
    for (int it = 0; it < 8; ++it) {
        int nl = g4 + it * 4;
        int nn = nl0 + nl;
        int yy = nn >> 7, xx = nn & 127;
        float acc = 0.f;
        #pragma unroll
        for (int k = 0; k < 24; ++k) {
            int kk = k + (k >= 12 ? 1 : 0);
            int q5 = (kk * 52) >> 8;
            int dy = q5 - 2, dx = kk - 5 * q5 - 2;
            int ny = min(max(yy + dy, 0), 127);
            int nx = min(max(xx + dx, 0), 127);
            int nb = (b << 14) + (ny << 7) + nx;
            acc = fmaf(wl[nl * 24 + k], msg[(size_t)nb * 64 + lane], acc);
        }
        aggL[nl][lane] = acc / sumw[nl];
    }

    float4 wo[16];
    #pragma unroll
    for (int c4 = 0; c4 < 16; ++c4) wo[c4] = ((const float4*)Wo)[lane * 16 + c4];
    __syncthreads();

    #pragma unroll
    for (int it = 0; it < 8; ++it) {
        int nl = g4 + it * 4;
        const float4* ar = (const float4*)aggL[nl];
        float a0 = 0.f, a1 = 0.f, a2 = 0.f, a3 = 0.f;
        #pragma unroll
        for (int c4 = 0; c4 < 16; ++c4) {
            float4 wv = wo[c4];
            float4 av = ar[c4];
            a0 = fmaf(av.x, wv.x, a0);
            a1 = fmaf(av.y, wv.y, a1);
            a2 = fmaf(av.z, wv.z, a2);
            a3 = fmaf(av.w, wv.w, a3);
        }
        float v = (a0 + a1) + (a2 + a3) + bo[lane]
                + x[(size_t)b * 64 * NNODES + (size_t)lane * NNODES + nl0 + nl];
        ot[lane][nl] = v;
    }
    __syncthreads();

    #pragma unroll
    for (int rep = 0; rep < 2; ++rep) {
        int idx = rep * 256 + t;
        int o = idx >> 3, p = idx & 7;
        float4 v = make_float4(ot[o][4 * p + 0], ot[o][4 * p + 1],
                               ot[o][4 * p + 2], ot[o][4 * p + 3]);
        *(float4*)(out + (size_t)b * 64 * NNODES + (size_t)o * NNODES + nl0 + 4 * p) = v;
    }
}

// ---------------------------------------------------------------------------
extern "C" void kernel_launch(void* const* d_in, const int* in_sizes, int n_in,
                              void* d_out, int out_size, void* d_ws, size_t ws_size,
                              hipStream_t stream)
{
    const float* x   = (const float*)d_in[0];
    const float* W1  = (const float*)d_in[1];
    const float* b1  = (const float*)d_in[2];
    const float* W2  = (const float*)d_in[3];
    const float* b2  = (const float*)d_in[4];
    const float* W3  = (const float*)d_in[5];
    const float* b3  = (const float*)d_in[6];
    const float* thr = (const float*)d_in[7];
    const float* Wm  = (const float*)d_in[8];
    const float* bm  = (const float*)d_in[9];
    const float* Wo  = (const float*)d_in[10];
    const float* bo  = (const float*)d_in[11];
    float* out = (float*)d_out;
    float* ws  = (float*)d_ws;

    // ws layout (floats): zsrc[2M] ztgt[2M] msg[2M] scores[768K] zpos[1536] wt[12288]
    float* zsrc   = ws;
    float* ztgt   = ws + 2097152;
    float* msg    = ws + 4194304;
    float* scores = ws + 6291456;
    float* zpos   = ws + 7077888;
    float* wt     = ws + 7079424;

    hipLaunchKernelGGL(aux_k, dim3(1), dim3(256), 0, stream, W1, Wm, zpos, wt);
    hipLaunchKernelGGL(precompute_k, dim3(768), dim3(128), 0, stream,
                       x, wt, b1, bm, zsrc, ztgt, msg);
    hipLaunchKernelGGL(score_k, dim3(1024), dim3(256), 0, stream,
                       zsrc, ztgt, zpos, W2, b2, W3, b3, scores);
    hipLaunchKernelGGL(agg_k, dim3(1024), dim3(256), 0, stream,
                       x, scores, msg, Wo, bo, thr, out);
}